// Round 6
// baseline (33.811 us; speedup 1.0000x reference)
//
#include <hip/hip_runtime.h>

// out[b,o,c,l] = time[b,c,l] * sum_{i,k} W[o,i,c,k] * x[b,i,c,l+k-1]  (x zero-padded in l)
// b=16, i=64, c=4, L=4096, o=64, K=3
//
// Single kernel. Block = one (b, c, 256-l range): 4 chunks of 64 l in ONE
// contiguous LDS buffer (258 rows [row = l-(lb0-1)][col = i] bf16, XOR-swz),
// inter-chunk halos free. Deep prefetch: chunks 2 AND 3 load before
// compute(0). W gathered in-kernel per wave (48 L2-hot dword loads, latency
// hidden under staging). time staged via LDS (1 coalesced load/thread).
// MFMA A=x B=W -> D row=l col=o; float4 epilogue.

#define NB 16
#define NI 64
#define NC 4
#define NL 4096
#define NO 64
#define KW 3
#define LT 64
#define NT 4
#define LBLK (LT * NT)        // 256 l per block
#define ROWS (LBLK + 2)       // 258
#define ROWB 128              // 64 i * 2B
#define TOFF (ROWS * ROWB)    // time region offset (33024)
#define LDSB (TOFF + LBLK * 4)

typedef float f32x4 __attribute__((ext_vector_type(4)));
typedef short bf16x8 __attribute__((ext_vector_type(8)));
typedef unsigned int u32x2 __attribute__((ext_vector_type(2)));

__device__ inline unsigned short f2bf(float f) {
    unsigned int u = __builtin_bit_cast(unsigned int, f);
    u += 0x7FFFu + ((u >> 16) & 1u);          // round-to-nearest-even
    return (unsigned short)(u >> 16);
}

// staging task: quad = lane&15 (l-quad), g = wave*4 + (lane>>4) (i-group of 4)
__device__ __forceinline__ void stage_load(const float* __restrict__ xb,
                                           int l0, int g, f32x4 s[4]) {
    const float* p = xb + (size_t)(4 * g) * (NC * NL) + l0;
    s[0] = *(const f32x4*)(p);
    s[1] = *(const f32x4*)(p + NC * NL);
    s[2] = *(const f32x4*)(p + 2 * NC * NL);
    s[3] = *(const f32x4*)(p + 3 * NC * NL);
}

__device__ __forceinline__ void stage_write(char* __restrict__ lds,
                                            int r0, int g, const f32x4 s[4]) {
#pragma unroll
    for (int r = 0; r < 4; ++r) {
        const int rr = r0 + r;
        u32x2 pk;
        pk[0] = (unsigned int)f2bf(s[0][r]) | ((unsigned int)f2bf(s[1][r]) << 16);
        pk[1] = (unsigned int)f2bf(s[2][r]) | ((unsigned int)f2bf(s[3][r]) << 16);
        *(u32x2*)(lds + rr * ROWB + ((8 * g) ^ ((rr & 7) << 4))) = pk;
    }
}

__device__ __forceinline__ void compute_store(const char* __restrict__ lds,
                                              const bf16x8 wfrag[6],
                                              float* __restrict__ ob,
                                              int t, int lb0, int lane) {
    const int lcol  = lane & 15;
    const int ksub2 = (lane >> 4) * 16;

    f32x4 tv[4];                                         // time from LDS (broadcast reads)
#pragma unroll
    for (int lt = 0; lt < 4; ++lt)
        tv[lt] = *(const f32x4*)(lds + TOFF + 4 * (t * LT + lt * 16 + (lane >> 4) * 4));

    f32x4 acc[4] = {};
#pragma unroll
    for (int lt = 0; lt < 4; ++lt) {
#pragma unroll
        for (int cc = 0; cc < 6; ++cc) {
            const int k    = cc >> 1;
            const int ih   = cc & 1;
            const int row  = t * LT + lt * 16 + lcol + k;
            const int colb = ih * 64 + ksub2;
            const int off  = row * ROWB + (colb ^ ((row & 7) << 4));
            const bf16x8 xf = *(const bf16x8*)(lds + off);
            acc[lt] = __builtin_amdgcn_mfma_f32_16x16x32_bf16(xf, wfrag[cc], acc[lt], 0, 0, 0);
        }
    }
#pragma unroll
    for (int lt = 0; lt < 4; ++lt) {
        const int l0 = lb0 + t * LT + lt * 16 + (lane >> 4) * 4;
        f32x4 r;
#pragma unroll
        for (int q = 0; q < 4; ++q) r[q] = acc[lt][q] * tv[lt][q];
        *(f32x4*)(ob + l0) = r;
    }
}

__global__ __launch_bounds__(256, 4)
void tconv_mfma_kernel(const float* __restrict__ x,
                       const float* __restrict__ tt,
                       const float* __restrict__ w,
                       float* __restrict__ out)
{
    __shared__ char lds[LDSB];                           // 34 048 B

    const int t    = threadIdx.x;
    const int lane = t & 63;
    const int wave = t >> 6;
    const int c    = blockIdx.y;
    const int b    = blockIdx.z;
    const int lb0  = blockIdx.x * LBLK;
    const int o0   = wave * 16;
    const int g    = wave * 4 + (lane >> 4);
    const int lq   = 4 * (lane & 15);

    const float* xb = x + ((size_t)b * NI * NC + c) * NL;
    const float* tb = tt + (size_t)(b * NC + c) * NL;
    float* ob = out + ((size_t)b * NO * NC + (size_t)(o0 + (lane & 15)) * NC + c) * NL;

    // ---- prologue: x chunks 0,1 + halo + time issue FIRST (critical path)
    f32x4 s0[4], s1[4];
    stage_load(xb, lb0 + 0 * LT + lq, g, s0);
    stage_load(xb, lb0 + 1 * LT + lq, g, s1);
    float h = 0.f; int hrow = 0, hcol = 0;
    if (t < 128) {
        const int which = t & 1;
        const int i     = t >> 1;
        hrow = which ? (LBLK + 1) : 0;
        hcol = 2 * i;
        const int lh = which ? (lb0 + LBLK) : (lb0 - 1);
        if (lh >= 0 && lh < NL) h = xb[(size_t)i * (NC * NL) + lh];
    }
    const float tval = tb[lb0 + t];

    // ---- W gather (latency hides under staging + sync): 48 L2-hot dwords
    bf16x8 wfrag[6];
    {
        const float* wl = w + (size_t)(o0 + (lane & 15)) * (NI * NC * KW)
                            + (size_t)((lane >> 4) * 8) * (NC * KW) + c * KW;
#pragma unroll
        for (int half = 0; half < 2; ++half) {
            float v[3][8];
#pragma unroll
            for (int cc3 = 0; cc3 < 3; ++cc3) {
                const int cc = half * 3 + cc3;
                const float* p = wl + (cc & 1) * (32 * NC * KW) + (cc >> 1);
#pragma unroll
                for (int j = 0; j < 8; ++j) v[cc3][j] = p[j * (NC * KW)];
            }
#pragma unroll
            for (int cc3 = 0; cc3 < 3; ++cc3) {
                bf16x8 a;
#pragma unroll
                for (int j = 0; j < 8; ++j) a[j] = (short)f2bf(v[cc3][j]);
                wfrag[half * 3 + cc3] = a;
            }
        }
    }

    // ---- writes for chunks 0,1 + halo + time
    stage_write(lds, 1 + 0 * LT + lq, g, s0);
    stage_write(lds, 1 + 1 * LT + lq, g, s1);
    if (t < 128)
        *(unsigned short*)(lds + hrow * ROWB + (hcol ^ ((hrow & 7) << 4))) = f2bf(h);
    *(float*)(lds + TOFF + 4 * t) = tval;
    __syncthreads();

    // ---- deep prefetch: chunks 2 AND 3 in flight before any compute
    stage_load(xb, lb0 + 2 * LT + lq, g, s0);
    stage_load(xb, lb0 + 3 * LT + lq, g, s1);

    compute_store(lds, wfrag, ob, 0, lb0, lane);
    stage_write(lds, 1 + 2 * LT + lq, g, s0);            // waits only chunk-2 loads
    __syncthreads();

    compute_store(lds, wfrag, ob, 1, lb0, lane);
    stage_write(lds, 1 + 3 * LT + lq, g, s1);
    __syncthreads();

    // ---- drain
    compute_store(lds, wfrag, ob, 2, lb0, lane);
    compute_store(lds, wfrag, ob, 3, lb0, lane);
}

extern "C" void kernel_launch(void* const* d_in, const int* in_sizes, int n_in,
                              void* d_out, int out_size, void* d_ws, size_t ws_size,
                              hipStream_t stream) {
    const float* x  = (const float*)d_in[0];
    const float* tt = (const float*)d_in[1];
    const float* w  = (const float*)d_in[2];
    float* out = (float*)d_out;

    dim3 block(256);
    dim3 grid(NL / LBLK, NC, NB);   // (16, 4, 16) = 1024 blocks
    tconv_mfma_kernel<<<grid, block, 0, stream>>>(x, tt, w, out);
}

// Round 7
// 33.477 us; speedup vs baseline: 1.0100x; 1.0100x over previous
//
#include <hip/hip_runtime.h>

// out[b,o,c,l] = time[b,c,l] * sum_{i,k} W[o,i,c,k] * x[b,i,c,l+k-1]  (x zero-padded in l)
// b=16, i=64, c=4, L=4096, o=64, K=3
//
// Block = one (b, c, 256-l range): 4 chunks of 64 l in ONE contiguous LDS
// buffer (258 rows [row = l-(lb0-1)][col = i] bf16, XOR-swz); halos free.
// Deep prefetch: chunks 2,3 load before compute(0). W prepacked to fragment
// order (6 coalesced b128/wave). KEY CHANGE vs r6: raw s_barrier with ONLY
// lgkmcnt(0) — no vmcnt(0) drain, so output stores and the chunk-3 prefetch
// stay in flight across barriers (compiler's per-register vmcnt covers the
// reg-staged loads). MFMA A=x B=W -> D row=l col=o; float4 epilogue.

#define NB 16
#define NI 64
#define NC 4
#define NL 4096
#define NO 64
#define KW 3
#define LT 64
#define NT 4
#define LBLK (LT * NT)        // 256 l per block
#define ROWS (LBLK + 2)       // 258
#define ROWB 128              // 64 i * 2B
#define TOFF (ROWS * ROWB)    // time region offset (33024)
#define LDSB (TOFF + LBLK * 4)

#define W_PACK_BYTES (NO * NI * NC * KW * 2)   // 98304

typedef float f32x4 __attribute__((ext_vector_type(4)));
typedef short bf16x8 __attribute__((ext_vector_type(8)));
typedef unsigned int u32x2 __attribute__((ext_vector_type(2)));

__device__ inline unsigned short f2bf(float f) {
    unsigned int u = __builtin_bit_cast(unsigned int, f);
    u += 0x7FFFu + ((u >> 16) & 1u);          // round-to-nearest-even
    return (unsigned short)(u >> 16);
}

// LDS-only barrier: make ds_writes visible, do NOT drain vmcnt (stores /
// prefetch loads stay outstanding). Compiler still inserts precise vmcnt
// waits where staged-load registers are consumed.
__device__ __forceinline__ void block_sync_lds() {
    asm volatile("s_waitcnt lgkmcnt(0)" ::: "memory");
    __builtin_amdgcn_s_barrier();
    asm volatile("" ::: "memory");
}

// ---- kernel 1: pack W. Coalesced READ (tid = w flat index), scattered 2B write.
// dest flat bf16 index = (((c*4 + wv)*6 + cc)*64 + lane)*8 + j  where
// o = wv*16 + (lane&15), i = (cc&1)*32 + (lane>>4)*8 + j, k = cc>>1
__global__ __launch_bounds__(256)
void prepack_w_kernel(const float* __restrict__ w, unsigned short* __restrict__ wp) {
    const int idx = blockIdx.x * 256 + threadIdx.x;      // 49152 = o*i*c*k
    const float v = w[idx];                              // coalesced
    const int k = idx % 3;
    int r = idx / 3;
    const int c = r & 3;  r >>= 2;
    const int i = r & 63;
    const int o = r >> 6;
    const int cc   = k * 2 + (i >> 5);
    const int lane = (((i >> 3) & 3) << 4) | (o & 15);
    const int j    = i & 7;
    const int wv   = o >> 4;
    wp[(((c * 4 + wv) * 6 + cc) * 64 + lane) * 8 + j] = f2bf(v);
}

// staging task: quad = lane&15 (l-quad), g = wave*4 + (lane>>4) (i-group of 4)
__device__ __forceinline__ void stage_load(const float* __restrict__ xb,
                                           int l0, int g, f32x4 s[4]) {
    const float* p = xb + (size_t)(4 * g) * (NC * NL) + l0;
    s[0] = *(const f32x4*)(p);
    s[1] = *(const f32x4*)(p + NC * NL);
    s[2] = *(const f32x4*)(p + 2 * NC * NL);
    s[3] = *(const f32x4*)(p + 3 * NC * NL);
}

__device__ __forceinline__ void stage_write(char* __restrict__ lds,
                                            int r0, int g, const f32x4 s[4]) {
#pragma unroll
    for (int r = 0; r < 4; ++r) {
        const int rr = r0 + r;
        u32x2 pk;
        pk[0] = (unsigned int)f2bf(s[0][r]) | ((unsigned int)f2bf(s[1][r]) << 16);
        pk[1] = (unsigned int)f2bf(s[2][r]) | ((unsigned int)f2bf(s[3][r]) << 16);
        *(u32x2*)(lds + rr * ROWB + ((8 * g) ^ ((rr & 7) << 4))) = pk;
    }
}

__device__ __forceinline__ void compute_store(const char* __restrict__ lds,
                                              const bf16x8 wfrag[6],
                                              float* __restrict__ ob,
                                              int t, int lb0, int lane) {
    const int lcol  = lane & 15;
    const int ksub2 = (lane >> 4) * 16;

    f32x4 tv[4];                                         // time from LDS
#pragma unroll
    for (int lt = 0; lt < 4; ++lt)
        tv[lt] = *(const f32x4*)(lds + TOFF + 4 * (t * LT + lt * 16 + (lane >> 4) * 4));

    f32x4 acc[4] = {};
#pragma unroll
    for (int lt = 0; lt < 4; ++lt) {
#pragma unroll
        for (int cc = 0; cc < 6; ++cc) {
            const int k    = cc >> 1;
            const int ih   = cc & 1;
            const int row  = t * LT + lt * 16 + lcol + k;
            const int colb = ih * 64 + ksub2;
            const int off  = row * ROWB + (colb ^ ((row & 7) << 4));
            const bf16x8 xf = *(const bf16x8*)(lds + off);
            acc[lt] = __builtin_amdgcn_mfma_f32_16x16x32_bf16(xf, wfrag[cc], acc[lt], 0, 0, 0);
        }
    }
#pragma unroll
    for (int lt = 0; lt < 4; ++lt) {
        const int l0 = lb0 + t * LT + lt * 16 + (lane >> 4) * 4;
        f32x4 r;
#pragma unroll
        for (int q = 0; q < 4; ++q) r[q] = acc[lt][q] * tv[lt][q];
        *(f32x4*)(ob + l0) = r;
    }
}

__global__ __launch_bounds__(256, 4)
void tconv_mfma_kernel(const float* __restrict__ x,
                       const float* __restrict__ tt,
                       const unsigned short* __restrict__ wp,
                       float* __restrict__ out)
{
    __shared__ char lds[LDSB];                           // 34 048 B

    const int t    = threadIdx.x;
    const int lane = t & 63;
    const int wave = t >> 6;
    const int c    = blockIdx.y;
    const int b    = blockIdx.z;
    const int lb0  = blockIdx.x * LBLK;
    const int o0   = wave * 16;
    const int g    = wave * 4 + (lane >> 4);
    const int lq   = 4 * (lane & 15);

    const float* xb = x + ((size_t)b * NI * NC + c) * NL;
    const float* tb = tt + (size_t)(b * NC + c) * NL;
    float* ob = out + ((size_t)b * NO * NC + (size_t)(o0 + (lane & 15)) * NC + c) * NL;

    // ---- prologue: x chunks 0,1 + halo + time issue first (HBM critical path)
    f32x4 s0[4], s1[4];
    stage_load(xb, lb0 + 0 * LT + lq, g, s0);
    stage_load(xb, lb0 + 1 * LT + lq, g, s1);
    float h = 0.f; int hrow = 0, hcol = 0;
    if (t < 128) {
        const int which = t & 1;
        const int i     = t >> 1;
        hrow = which ? (LBLK + 1) : 0;
        hcol = 2 * i;
        const int lh = which ? (lb0 + LBLK) : (lb0 - 1);
        if (lh >= 0 && lh < NL) h = xb[(size_t)i * (NC * NL) + lh];
    }
    const float tval = tb[lb0 + t];

    // ---- W fragments: 6 coalesced b128, L2-hot (latency hides under x loads)
    bf16x8 wfrag[6];
    {
        const bf16x8* wpb = (const bf16x8*)wp + (size_t)((c * 4 + wave) * 6) * 64 + lane;
#pragma unroll
        for (int cc = 0; cc < 6; ++cc) wfrag[cc] = wpb[cc * 64];
    }

    // ---- writes for chunks 0,1 + halo + time
    stage_write(lds, 1 + 0 * LT + lq, g, s0);
    stage_write(lds, 1 + 1 * LT + lq, g, s1);
    if (t < 128)
        *(unsigned short*)(lds + hrow * ROWB + (hcol ^ ((hrow & 7) << 4))) = f2bf(h);
    *(float*)(lds + TOFF + 4 * t) = tval;
    block_sync_lds();

    // ---- deep prefetch: chunks 2 AND 3 in flight before any compute
    stage_load(xb, lb0 + 2 * LT + lq, g, s0);
    stage_load(xb, lb0 + 3 * LT + lq, g, s1);

    compute_store(lds, wfrag, ob, 0, lb0, lane);
    stage_write(lds, 1 + 2 * LT + lq, g, s0);            // waits only chunk-2 regs
    block_sync_lds();

    compute_store(lds, wfrag, ob, 1, lb0, lane);
    stage_write(lds, 1 + 3 * LT + lq, g, s1);
    block_sync_lds();

    // ---- drain
    compute_store(lds, wfrag, ob, 2, lb0, lane);
    compute_store(lds, wfrag, ob, 3, lb0, lane);
}

extern "C" void kernel_launch(void* const* d_in, const int* in_sizes, int n_in,
                              void* d_out, int out_size, void* d_ws, size_t ws_size,
                              hipStream_t stream) {
    const float* x  = (const float*)d_in[0];
    const float* tt = (const float*)d_in[1];
    const float* w  = (const float*)d_in[2];
    float* out = (float*)d_out;
    unsigned short* wpck = (unsigned short*)d_ws;

    dim3 block(256);
    prepack_w_kernel<<<dim3(NO * NI * NC * KW / 256), block, 0, stream>>>(w, wpck);

    dim3 grid(NL / LBLK, NC, NB);   // (16, 4, 16) = 1024 blocks
    tconv_mfma_kernel<<<grid, block, 0, stream>>>(x, tt, wpck, out);
}